// Round 6
// baseline (117.376 us; speedup 1.0000x reference)
//
#include <hip/hip_runtime.h>
#include <math.h>

#define NPTS 262144
#define K 32
#define D 16
#define R 272            // contraction dim: 256 quad (all d,f) + 16 linear
#define NTILES (NPTS/32) // 8192 tiles of 32 points
#define NBLK 1024        // 4 waves/block, 2 tiles/wave -> 8192 tiles
#define LROW 544         // 272 bf16 = 34 x 16B granules per theta row
#define LHALF 17408      // 32 rows * 544 B ; thetaL LDS region offset
#define REPS 2           // INSTRUMENTATION: double work so the density kernel
                         // enters rocprof top-5 (fills are ~43us). Remove next round.

typedef __attribute__((ext_vector_type(8))) short bf16x8;   // 8 bf16 = 4 VGPR
typedef __attribute__((ext_vector_type(16))) float f32x16;  // MFMA acc
typedef __attribute__((ext_vector_type(4))) int int4v;

// ---------------- prep kernel: one block per component k ----------------
// All math in double. Produces, pre-scaled by log2(e):
//   Theta[k][r] : r<256 -> -0.5*L[d=r>>4][f=r&15] ; r in [256,272) -> (L m)[r-256]
//   split into bf16 hi (truncation) + bf16 lo (residual) arrays, plus
//   lc[k] = logsoftmax(p)_k - 8 log(2pi) + log sqrt(det L) - 0.5 m^T L m
// so density(x) = sum_k exp2( lc_k + Theta_k . phi(x) ),
// phi(x) = [x_d x_f (256), x_d (16)].
__global__ __launch_bounds__(256) void gm_prep_kernel(
    const float* __restrict__ m_w,      // K*D
    const float* __restrict__ l_fac,    // K*D*D
    const float* __restrict__ p_logits, // K
    unsigned short* __restrict__ thetaH, // K*R bf16 bits
    unsigned short* __restrict__ thetaL, // K*R bf16 bits
    float* __restrict__ lc_out)          // K
{
  const int k = blockIdx.x;
  const int tid = threadIdx.x;
  const int r = tid >> 4, c = tid & 15;
  __shared__ double A[D][D];
  __shared__ double L[D][D];
  __shared__ double W[D][D];   // Cholesky workspace
  __shared__ double Gd[D];
  __shared__ double sm[K + 1]; // softmax terms + max
  __shared__ double ld[D];     // log-diag terms
  const double LOG2E = 1.4426950408889634074;

  A[r][c] = (double)l_fac[k * D * D + r * D + c];
  __syncthreads();

  // L = A A^T / D
  {
    double s = 0.0;
    #pragma unroll
    for (int e = 0; e < D; ++e) s += A[r][e] * A[c][e];
    s /= (double)D;
    L[r][c] = s;
    W[r][c] = s;
  }
  __syncthreads();

  // G = L m (kept in double for the m^T L m fold)
  if (tid < D) {
    double s = 0.0;
    #pragma unroll
    for (int f = 0; f < D; ++f) s += L[tid][f] * (double)m_w[k * D + f];
    Gd[tid] = s;
  }
  if (tid == 0) {
    double mx = -1e300;
    for (int i = 0; i < K; ++i) mx = fmax(mx, (double)p_logits[i]);
    sm[K] = mx;
  }

  // Cholesky of W for log sqrt(det L) = sum log W_jj
  for (int j = 0; j < D; ++j) {
    __syncthreads();
    if (tid == 0) W[j][j] = sqrt(W[j][j]);
    __syncthreads();
    if (tid > j && tid < D) W[tid][j] /= W[j][j];
    __syncthreads();
    if (r > j && c > j && c <= r) W[r][c] -= W[r][j] * W[c][j];
  }
  __syncthreads();

  // parallel transcendentals (was a serial tid==0 section)
  if (tid < K) sm[tid] = exp((double)p_logits[tid] - sm[K]);
  if (tid < D) ld[tid] = log(W[tid][tid]);
  __syncthreads();

  if (tid == 0) {
    double z = 0.0;
    for (int i = 0; i < K; ++i) z += sm[i];
    double logdet_sqrtL = 0.0;
    for (int j = 0; j < D; ++j) logdet_sqrtL += ld[j];
    double logp = (double)p_logits[k] - sm[K] - log(z);
    double cc = 0.0;                       // m^T L m
    for (int d2 = 0; d2 < D; ++d2) cc += (double)m_w[k * D + d2] * Gd[d2];
    double lc = logp - 8.0 * log(2.0 * M_PI) + logdet_sqrtL - 0.5 * cc;
    lc_out[k] = (float)(LOG2E * lc);
  }
  __syncthreads();

  // Theta entries, hi/lo bf16 split (truncation; lo absorbs the residual)
  for (int q = tid; q < R; q += 256) {
    double th = (q < 256) ? (-0.5 * LOG2E) * L[q >> 4][q & 15]
                          : LOG2E * Gd[q - 256];
    float tf = (float)th;
    unsigned u = __float_as_uint(tf);
    float hi = __uint_as_float(u & 0xFFFF0000u);
    float lo = tf - hi;
    thetaH[k * R + q] = (unsigned short)(u >> 16);
    thetaL[k * R + q] = (unsigned short)(__float_as_uint(lo) >> 16);
  }
}

// pack 2 floats -> 2 bf16 (truncation) in one dword
__device__ __forceinline__ int pack_bf16_hi(unsigned u0, unsigned u1) {
  return (int)__builtin_amdgcn_perm(u1, u0, 0x07060302u);
}

// ---------------- density kernel: MFMA over phi(x), theta in LDS ----------------
// Theta (hi+lo) staged into LDS with a 16B-granule XOR swizzle
// (phys = m ^ (row&7) ^ (row>>3) for m<32) so the per-step ds_read_b128
// (lane row = lane&31, stride 544 B) is bank-conflict-free.
// Fragments: A = theta row p (comp), k-slot kh*8+j; B = phi built in-register.
// D layout: col=lane&31 (point), row=(reg&3)+8*(reg>>2)+4*kh (comp).
// Two accumulators split the 51-MFMA dependent chain (A: TH*ph + TH*pl,
// B: TL*ph) -> exposed MFMA latency halves.
__global__ __launch_bounds__(256, 4) void gm_mfma_kernel(
    const float* __restrict__ x,              // N*D
    const unsigned short* __restrict__ thetaH,
    const unsigned short* __restrict__ thetaL,
    const float* __restrict__ lc,             // K
    float* __restrict__ out)                  // N
{
  __shared__ __align__(16) char lth[2 * LHALF];
  const int tid = threadIdx.x;
  const int lane = tid & 63;
  const int p = lane & 31;          // point within tile / comp row for A
  const int kh = lane >> 5;         // k-half within 16-wide step

  // ---- stage theta -> LDS (swizzled), 2176 16B chunks ----
  for (int j = tid; j < 2176; j += 256) {
    int half = (j >= 1088) ? 1 : 0;
    int jj = half ? j - 1088 : j;
    int row = jj / 34;
    int m = jj - row * 34;
    int sig = (row & 7) ^ (row >> 3);
    int phys = (m < 32) ? (m ^ sig) : m;
    const char* src = (const char*)(half ? thetaL : thetaH) + (size_t)jj * 16;
    int4v v = *(const int4v*)src;
    *(int4v*)(lth + half * LHALF + row * LROW + phys * 16) = v;
  }

  // lc per accumulator register: comp = (i&3) + 8*(i>>2) + 4*kh
  float lcv[16];
  #pragma unroll
  for (int i = 0; i < 16; ++i)
    lcv[i] = lc[(i & 3) + 8 * (i >> 2) + 4 * kh];

  __syncthreads();

  // per-lane swizzled read bases: slot m = kh + 2s, phys = m ^ sig
  // addr = p*544 + 16*((kh^(sig&1)) | ((2s)^(sig&6))) = base2 + ((s*32) ^ E)
  const int sig = (p & 7) ^ (p >> 3);
  const int base2 = p * LROW + ((kh ^ (sig & 1)) << 4);
  const int E = (sig & 6) << 4;
  const int baseT = p * LROW + 512 + (kh << 4);   // tail slot m=32+kh (no swizzle)

  const int t0 = (blockIdx.x * 4 + (tid >> 6)) * 2;

  for (int rep = 0; rep < REPS; ++rep) {
  for (int tt = 0; tt < 2; ++tt) {
    const int t = t0 + tt;
    // load this lane's point (half-waves share addresses -> broadcast)
    const float4* xp = (const float4*)(x + ((size_t)t * 32 + p) * D);
    float xs[16];
    #pragma unroll
    for (int i = 0; i < 4; ++i) {
      float4 v = xp[i];
      xs[4 * i + 0] = v.x; xs[4 * i + 1] = v.y;
      xs[4 * i + 2] = v.z; xs[4 * i + 3] = v.w;
    }
    float xf[8];
    #pragma unroll
    for (int j = 0; j < 8; ++j) xf[j] = kh ? xs[8 + j] : xs[j];

    f32x16 accA, accB;
    #pragma unroll
    for (int i = 0; i < 16; ++i) { accA[i] = 0.f; accB[i] = 0.f; }

    // quad steps s=0..15: phi_r = x_s * x_f, hi/lo split by truncation
    #pragma unroll
    for (int s = 0; s < 16; ++s) {
      const int va = base2 + ((s * 32) ^ E);
      int4v thv = *(const int4v*)(lth + va);
      int4v tlv = *(const int4v*)(lth + va + LHALF);
      int4v ph, pl;
      #pragma unroll
      for (int a = 0; a < 4; ++a) {
        float p0 = xs[s] * xf[2 * a];
        float p1 = xs[s] * xf[2 * a + 1];
        unsigned u0 = __float_as_uint(p0), u1 = __float_as_uint(p1);
        ph[a] = pack_bf16_hi(u0, u1);
        float h0 = __uint_as_float(u0 & 0xFFFF0000u);
        float h1 = __uint_as_float(u1 & 0xFFFF0000u);
        pl[a] = pack_bf16_hi(__float_as_uint(p0 - h0), __float_as_uint(p1 - h1));
      }
      accA = __builtin_amdgcn_mfma_f32_32x32x16_bf16(
          __builtin_bit_cast(bf16x8, thv), __builtin_bit_cast(bf16x8, ph), accA, 0, 0, 0);
      accB = __builtin_amdgcn_mfma_f32_32x32x16_bf16(
          __builtin_bit_cast(bf16x8, tlv), __builtin_bit_cast(bf16x8, ph), accB, 0, 0, 0);
      accA = __builtin_amdgcn_mfma_f32_32x32x16_bf16(
          __builtin_bit_cast(bf16x8, thv), __builtin_bit_cast(bf16x8, pl), accA, 0, 0, 0);
    }
    // linear step: phi_r = x_f
    {
      int4v thv = *(const int4v*)(lth + baseT);
      int4v tlv = *(const int4v*)(lth + baseT + LHALF);
      int4v ph, pl;
      #pragma unroll
      for (int a = 0; a < 4; ++a) {
        float p0 = xf[2 * a], p1 = xf[2 * a + 1];
        unsigned u0 = __float_as_uint(p0), u1 = __float_as_uint(p1);
        ph[a] = pack_bf16_hi(u0, u1);
        float h0 = __uint_as_float(u0 & 0xFFFF0000u);
        float h1 = __uint_as_float(u1 & 0xFFFF0000u);
        pl[a] = pack_bf16_hi(__float_as_uint(p0 - h0), __float_as_uint(p1 - h1));
      }
      accA = __builtin_amdgcn_mfma_f32_32x32x16_bf16(
          __builtin_bit_cast(bf16x8, thv), __builtin_bit_cast(bf16x8, ph), accA, 0, 0, 0);
      accB = __builtin_amdgcn_mfma_f32_32x32x16_bf16(
          __builtin_bit_cast(bf16x8, tlv), __builtin_bit_cast(bf16x8, ph), accB, 0, 0, 0);
      accA = __builtin_amdgcn_mfma_f32_32x32x16_bf16(
          __builtin_bit_cast(bf16x8, thv), __builtin_bit_cast(bf16x8, pl), accA, 0, 0, 0);
    }

    // epilogue: exp2 per comp, sum 16 local comps, one cross-half add
    float e[16];
    #pragma unroll
    for (int i = 0; i < 16; ++i)
      e[i] = __builtin_amdgcn_exp2f(accA[i] + accB[i] + lcv[i]);
    float a0 = (e[0] + e[1]) + (e[2] + e[3]);
    float a1 = (e[4] + e[5]) + (e[6] + e[7]);
    float a2 = (e[8] + e[9]) + (e[10] + e[11]);
    float a3 = (e[12] + e[13]) + (e[14] + e[15]);
    float ss = (a0 + a1) + (a2 + a3);
    ss += __shfl_xor(ss, 32);
    if (lane < 32) out[(size_t)t * 32 + p] = ss;
  }
  }
}

extern "C" void kernel_launch(void* const* d_in, const int* in_sizes, int n_in,
                              void* d_out, int out_size, void* d_ws, size_t ws_size,
                              hipStream_t stream) {
  const float* x        = (const float*)d_in[0];
  const float* m_w      = (const float*)d_in[1];
  const float* l_fac    = (const float*)d_in[2];
  const float* p_logits = (const float*)d_in[3];
  float* out = (float*)d_out;

  char* ws = (char*)d_ws;
  unsigned short* thetaH = (unsigned short*)(ws);                 // 17408 B
  unsigned short* thetaL = (unsigned short*)(ws + K * R * 2);     // 17408 B
  float* lc              = (float*)(ws + 2 * K * R * 2);          // 128 B

  gm_prep_kernel<<<K, 256, 0, stream>>>(m_w, l_fac, p_logits, thetaH, thetaL, lc);
  gm_mfma_kernel<<<NBLK, 256, 0, stream>>>(x, thetaH, thetaL, lc, out);
}

// Round 7
// 34.485 us; speedup vs baseline: 3.4037x; 3.4037x over previous
//
#include <hip/hip_runtime.h>
#include <math.h>

#define NPTS 262144
#define K 32
#define D 16
#define R 272            // contraction dim: 256 quad (all d,f) + 16 linear
#define NTILES (NPTS/32) // 8192 tiles of 32 points
#define NBLK 2048        // 4 waves/block, 1 tile/wave -> 8192 tiles
#define LROW 544         // 272 bf16 = 34 x 16B granules per theta row
#define LHALF 17408      // 32 rows * 544 B ; thetaL LDS region offset

typedef __attribute__((ext_vector_type(8))) short bf16x8;   // 8 bf16 = 4 VGPR
typedef __attribute__((ext_vector_type(16))) float f32x16;  // MFMA acc
typedef __attribute__((ext_vector_type(4))) int int4v;

// ---------------- prep kernel: one block per component k ----------------
// All math in double. Produces, pre-scaled by log2(e):
//   Theta[k][r] : r<256 -> -0.5*L[d=r>>4][f=r&15] ; r in [256,272) -> (L m)[r-256]
//   split into bf16 hi (truncation) + bf16 lo (residual) arrays, plus
//   lc[k] = logsoftmax(p)_k - 8 log(2pi) + log sqrt(det L) - 0.5 m^T L m
// so density(x) = sum_k exp2( lc_k + Theta_k . phi(x) ),
// phi(x) = [x_d x_f (256), x_d (16)].
__global__ __launch_bounds__(256) void gm_prep_kernel(
    const float* __restrict__ m_w,      // K*D
    const float* __restrict__ l_fac,    // K*D*D
    const float* __restrict__ p_logits, // K
    unsigned short* __restrict__ thetaH, // K*R bf16 bits
    unsigned short* __restrict__ thetaL, // K*R bf16 bits
    float* __restrict__ lc_out)          // K
{
  const int k = blockIdx.x;
  const int tid = threadIdx.x;
  const int r = tid >> 4, c = tid & 15;
  __shared__ double A[D][D];
  __shared__ double L[D][D];
  __shared__ double W[D][D];   // Cholesky workspace
  __shared__ double Gd[D];
  __shared__ double sm[K + 1]; // softmax terms + max
  __shared__ double ld[D];     // log-diag terms
  const double LOG2E = 1.4426950408889634074;

  A[r][c] = (double)l_fac[k * D * D + r * D + c];
  __syncthreads();

  // L = A A^T / D
  {
    double s = 0.0;
    #pragma unroll
    for (int e = 0; e < D; ++e) s += A[r][e] * A[c][e];
    s /= (double)D;
    L[r][c] = s;
    W[r][c] = s;
  }
  __syncthreads();

  // G = L m (kept in double for the m^T L m fold)
  if (tid < D) {
    double s = 0.0;
    #pragma unroll
    for (int f = 0; f < D; ++f) s += L[tid][f] * (double)m_w[k * D + f];
    Gd[tid] = s;
  }
  if (tid == 0) {
    double mx = -1e300;
    for (int i = 0; i < K; ++i) mx = fmax(mx, (double)p_logits[i]);
    sm[K] = mx;
  }

  // Cholesky of W for log sqrt(det L) = sum log W_jj
  for (int j = 0; j < D; ++j) {
    __syncthreads();
    if (tid == 0) W[j][j] = sqrt(W[j][j]);
    __syncthreads();
    if (tid > j && tid < D) W[tid][j] /= W[j][j];
    __syncthreads();
    if (r > j && c > j && c <= r) W[r][c] -= W[r][j] * W[c][j];
  }
  __syncthreads();

  // parallel transcendentals (was a serial tid==0 section)
  if (tid < K) sm[tid] = exp((double)p_logits[tid] - sm[K]);
  if (tid < D) ld[tid] = log(W[tid][tid]);
  __syncthreads();

  if (tid == 0) {
    double z = 0.0;
    for (int i = 0; i < K; ++i) z += sm[i];
    double logdet_sqrtL = 0.0;
    for (int j = 0; j < D; ++j) logdet_sqrtL += ld[j];
    double logp = (double)p_logits[k] - sm[K] - log(z);
    double cc = 0.0;                       // m^T L m
    for (int d2 = 0; d2 < D; ++d2) cc += (double)m_w[k * D + d2] * Gd[d2];
    double lc = logp - 8.0 * log(2.0 * M_PI) + logdet_sqrtL - 0.5 * cc;
    lc_out[k] = (float)(LOG2E * lc);
  }
  __syncthreads();

  // Theta entries, hi/lo bf16 split (truncation; lo absorbs the residual)
  for (int q = tid; q < R; q += 256) {
    double th = (q < 256) ? (-0.5 * LOG2E) * L[q >> 4][q & 15]
                          : LOG2E * Gd[q - 256];
    float tf = (float)th;
    unsigned u = __float_as_uint(tf);
    float hi = __uint_as_float(u & 0xFFFF0000u);
    float lo = tf - hi;
    thetaH[k * R + q] = (unsigned short)(u >> 16);
    thetaL[k * R + q] = (unsigned short)(__float_as_uint(lo) >> 16);
  }
}

// pack 2 floats -> 2 bf16 (truncation) in one dword
__device__ __forceinline__ int pack_bf16_hi(unsigned u0, unsigned u1) {
  return (int)__builtin_amdgcn_perm(u1, u0, 0x07060302u);
}

// ---------------- density kernel: MFMA over phi(x), theta in LDS ----------------
// Theta (hi+lo) staged into LDS with a 16B-granule XOR swizzle
// (phys = m ^ (row&7) ^ (row>>3) for m<32) so the per-step ds_read_b128
// (lane row = lane&31, stride 544 B) is low-conflict.
// Fragments: A = theta row p (comp), k-slot kh*8+j; B = phi built in-register.
// D layout: col=lane&31 (point), row=(reg&3)+8*(reg>>2)+4*kh (comp).
// NO min-waves launch bound: round-6 counters showed __launch_bounds__(256,4)
// capped VGPRs at 128 < demand -> 420 MB/dispatch scratch spill traffic.
// Plain (256) sets the allocator limit to 512: spilling impossible.
__global__ __launch_bounds__(256) void gm_mfma_kernel(
    const float* __restrict__ x,              // N*D
    const unsigned short* __restrict__ thetaH,
    const unsigned short* __restrict__ thetaL,
    const float* __restrict__ lc,             // K
    float* __restrict__ out)                  // N
{
  __shared__ __align__(16) char lth[2 * LHALF];
  const int tid = threadIdx.x;
  const int lane = tid & 63;
  const int p = lane & 31;          // point within tile / comp row for A
  const int kh = lane >> 5;         // k-half within 16-wide step

  // ---- stage theta -> LDS (swizzled), 2176 16B chunks ----
  for (int j = tid; j < 2176; j += 256) {
    int half = (j >= 1088) ? 1 : 0;
    int jj = half ? j - 1088 : j;
    int row = jj / 34;
    int m = jj - row * 34;
    int sig = (row & 7) ^ (row >> 3);
    int phys = (m < 32) ? (m ^ sig) : m;
    const char* src = (const char*)(half ? thetaL : thetaH) + (size_t)jj * 16;
    int4v v = *(const int4v*)src;
    *(int4v*)(lth + half * LHALF + row * LROW + phys * 16) = v;
  }

  // lc per accumulator register: comp = (i&3) + 8*(i>>2) + 4*kh
  float lcv[16];
  #pragma unroll
  for (int i = 0; i < 16; ++i)
    lcv[i] = lc[(i & 3) + 8 * (i >> 2) + 4 * kh];

  __syncthreads();

  // per-lane swizzled read bases: slot m = kh + 2s, phys = m ^ sig
  // addr = p*544 + 16*((kh^(sig&1)) | ((2s)^(sig&6))) = base2 + ((s*32) ^ E)
  const int sig = (p & 7) ^ (p >> 3);
  const int base2 = p * LROW + ((kh ^ (sig & 1)) << 4);
  const int E = (sig & 6) << 4;
  const int baseT = p * LROW + 512 + (kh << 4);   // tail slot m=32+kh (no swizzle)

  const int t = blockIdx.x * 4 + (tid >> 6);   // one tile per wave

  // load this lane's point (half-waves share addresses -> broadcast)
  const float4* xp = (const float4*)(x + ((size_t)t * 32 + p) * D);
  float xs[16];
  #pragma unroll
  for (int i = 0; i < 4; ++i) {
    float4 v = xp[i];
    xs[4 * i + 0] = v.x; xs[4 * i + 1] = v.y;
    xs[4 * i + 2] = v.z; xs[4 * i + 3] = v.w;
  }
  float xf[8];
  #pragma unroll
  for (int j = 0; j < 8; ++j) xf[j] = kh ? xs[8 + j] : xs[j];

  f32x16 acc;
  #pragma unroll
  for (int i = 0; i < 16; ++i) acc[i] = 0.f;

  // quad steps s=0..15: phi_r = x_s * x_f, hi/lo split by truncation
  #pragma unroll
  for (int s = 0; s < 16; ++s) {
    const int va = base2 + ((s * 32) ^ E);
    int4v thv = *(const int4v*)(lth + va);
    int4v tlv = *(const int4v*)(lth + va + LHALF);
    int4v ph, pl;
    #pragma unroll
    for (int a = 0; a < 4; ++a) {
      float p0 = xs[s] * xf[2 * a];
      float p1 = xs[s] * xf[2 * a + 1];
      unsigned u0 = __float_as_uint(p0), u1 = __float_as_uint(p1);
      ph[a] = pack_bf16_hi(u0, u1);
      float h0 = __uint_as_float(u0 & 0xFFFF0000u);
      float h1 = __uint_as_float(u1 & 0xFFFF0000u);
      pl[a] = pack_bf16_hi(__float_as_uint(p0 - h0), __float_as_uint(p1 - h1));
    }
    acc = __builtin_amdgcn_mfma_f32_32x32x16_bf16(
        __builtin_bit_cast(bf16x8, thv), __builtin_bit_cast(bf16x8, ph), acc, 0, 0, 0);
    acc = __builtin_amdgcn_mfma_f32_32x32x16_bf16(
        __builtin_bit_cast(bf16x8, tlv), __builtin_bit_cast(bf16x8, ph), acc, 0, 0, 0);
    acc = __builtin_amdgcn_mfma_f32_32x32x16_bf16(
        __builtin_bit_cast(bf16x8, thv), __builtin_bit_cast(bf16x8, pl), acc, 0, 0, 0);
  }
  // linear step: phi_r = x_f
  {
    int4v thv = *(const int4v*)(lth + baseT);
    int4v tlv = *(const int4v*)(lth + baseT + LHALF);
    int4v ph, pl;
    #pragma unroll
    for (int a = 0; a < 4; ++a) {
      float p0 = xf[2 * a], p1 = xf[2 * a + 1];
      unsigned u0 = __float_as_uint(p0), u1 = __float_as_uint(p1);
      ph[a] = pack_bf16_hi(u0, u1);
      float h0 = __uint_as_float(u0 & 0xFFFF0000u);
      float h1 = __uint_as_float(u1 & 0xFFFF0000u);
      pl[a] = pack_bf16_hi(__float_as_uint(p0 - h0), __float_as_uint(p1 - h1));
    }
    acc = __builtin_amdgcn_mfma_f32_32x32x16_bf16(
        __builtin_bit_cast(bf16x8, thv), __builtin_bit_cast(bf16x8, ph), acc, 0, 0, 0);
    acc = __builtin_amdgcn_mfma_f32_32x32x16_bf16(
        __builtin_bit_cast(bf16x8, tlv), __builtin_bit_cast(bf16x8, ph), acc, 0, 0, 0);
    acc = __builtin_amdgcn_mfma_f32_32x32x16_bf16(
        __builtin_bit_cast(bf16x8, thv), __builtin_bit_cast(bf16x8, pl), acc, 0, 0, 0);
  }

  // epilogue: exp2 per comp, sum 16 local comps, one cross-half add
  float e[16];
  #pragma unroll
  for (int i = 0; i < 16; ++i)
    e[i] = __builtin_amdgcn_exp2f(acc[i] + lcv[i]);
  float a0 = (e[0] + e[1]) + (e[2] + e[3]);
  float a1 = (e[4] + e[5]) + (e[6] + e[7]);
  float a2 = (e[8] + e[9]) + (e[10] + e[11]);
  float a3 = (e[12] + e[13]) + (e[14] + e[15]);
  float ss = (a0 + a1) + (a2 + a3);
  ss += __shfl_xor(ss, 32);
  if (lane < 32) out[(size_t)t * 32 + p] = ss;
}

extern "C" void kernel_launch(void* const* d_in, const int* in_sizes, int n_in,
                              void* d_out, int out_size, void* d_ws, size_t ws_size,
                              hipStream_t stream) {
  const float* x        = (const float*)d_in[0];
  const float* m_w      = (const float*)d_in[1];
  const float* l_fac    = (const float*)d_in[2];
  const float* p_logits = (const float*)d_in[3];
  float* out = (float*)d_out;

  char* ws = (char*)d_ws;
  unsigned short* thetaH = (unsigned short*)(ws);                 // 17408 B
  unsigned short* thetaL = (unsigned short*)(ws + K * R * 2);     // 17408 B
  float* lc              = (float*)(ws + 2 * K * R * 2);          // 128 B

  gm_prep_kernel<<<K, 256, 0, stream>>>(m_w, l_fac, p_logits, thetaH, thetaL, lc);
  gm_mfma_kernel<<<NBLK, 256, 0, stream>>>(x, thetaH, thetaL, lc, out);
}

// Round 8
// 23.051 us; speedup vs baseline: 5.0920x; 1.4960x over previous
//
#include <hip/hip_runtime.h>
#include <math.h>
#include <utility>

#define NPTS 262144
#define K 32
#define D 16
#define R 160            // 136 triangle + 16 linear + 8 pad -> 10 MFMA K-steps
#define NSTEPS 10
#define NTILES (NPTS/32) // 8192 tiles of 32 points
#define NBLK 1024        // 4 waves/block, 2 tiles/wave -> 8192 tiles
#define LROW 352         // 20 data granules (320 B) + 2 pad granules per row
#define LHALF 11264      // 32 rows * 352 B ; thetaL LDS region offset

typedef __attribute__((ext_vector_type(8))) short bf16x8;
typedef __attribute__((ext_vector_type(16))) float f32x16;
typedef __attribute__((ext_vector_type(4))) int int4v;

// ---- compile-time slot table -------------------------------------------
// Slot r in [0,160): pair (pd,pf).  pf==16 => linear term (phi = x_pd * 1),
// pd==17 => pad (phi=0, theta=0).  Slot r maps to MFMA step S=r>>4, lane
// half kh=(r>>3)&1, reg j=r&7.  a0/b0 = pair for kh=0, a1/b1 for kh=1.
struct PTab {
  short pd[160], pf[160];
  short a0[80], b0[80], a1[80], b1[80];
  constexpr PTab() : pd{}, pf{}, a0{}, b0{}, a1{}, b1{} {
    int n = 0;
    for (int d = 0; d < 16; ++d)
      for (int f = d; f < 16; ++f) { pd[n] = (short)d; pf[n] = (short)f; ++n; }
    for (int d = 0; d < 16; ++d) { pd[n] = (short)d; pf[n] = 16; ++n; }
    for (; n < 160; ++n) { pd[n] = 17; pf[n] = 17; }
    for (int s = 0; s < 10; ++s)
      for (int j = 0; j < 8; ++j) {
        a0[s*8+j] = pd[s*16+j];     b0[s*8+j] = pf[s*16+j];
        a1[s*8+j] = pd[s*16+8+j];   b1[s*8+j] = pf[s*16+8+j];
      }
  }
};
static constexpr PTab TAB{};

// ---------------- prep kernel: one block per component k ----------------
// fp32 throughout (error budget: theta split truncation 1.5e-5 rel dominates;
// fp32 adds ~1e-6-rel terms -> negligible vs 8.4e-13 abs threshold).
// LDL (no sqrt) with double-buffered Schur complement: 1 sync per step.
__global__ __launch_bounds__(256) void gm_prep_kernel(
    const float* __restrict__ m_w,      // K*D
    const float* __restrict__ l_fac,    // K*D*D
    const float* __restrict__ p_logits, // K
    unsigned short* __restrict__ thetaH, // K*R bf16 bits
    unsigned short* __restrict__ thetaL, // K*R bf16 bits
    float* __restrict__ lc_out)          // K
{
  const int k = blockIdx.x;
  const int tid = threadIdx.x;
  const int r = tid >> 4, c = tid & 15;
  __shared__ float A[D][D];
  __shared__ float L[D][D];
  __shared__ float S[2][D][D];   // LDL double buffer
  __shared__ float Gd[D];
  __shared__ float ld[D];        // log pivots
  __shared__ float sm[K];
  const float LOG2E = 1.4426950408889634f;

  A[r][c] = l_fac[k * D * D + r * D + c];
  if (tid < K) sm[tid] = p_logits[tid];
  __syncthreads();

  // L = A A^T / D
  {
    float s = 0.f;
    #pragma unroll
    for (int e = 0; e < D; ++e) s += A[r][e] * A[c][e];
    s *= (1.0f / D);
    L[r][c] = s;
    S[0][r][c] = s;
  }
  __syncthreads();

  // G = L m
  if (tid < D) {
    float s = 0.f;
    #pragma unroll
    for (int f = 0; f < D; ++f) s += L[tid][f] * m_w[k * D + f];
    Gd[tid] = s;
  }

  // LDL pivots via Schur complements, 1 sync per step (write other buffer)
  int cb = 0;
  for (int j = 0; j < 15; ++j) {
    float pj = S[cb][j][j];
    float a = S[cb][r][j], b = S[cb][c][j], v = S[cb][r][c];
    if (tid == 0) ld[j] = logf(pj);
    if (r > j && c > j) S[cb ^ 1][r][c] = v - a * b / pj;
    cb ^= 1;
    __syncthreads();
  }
  if (tid == 0) {
    ld[15] = logf(S[cb][15][15]);
    float mx = -1e30f;
    for (int i = 0; i < K; ++i) mx = fmaxf(mx, sm[i]);
    float z = 0.f;
    for (int i = 0; i < K; ++i) z += expf(sm[i] - mx);
    float logp = sm[k] - mx - logf(z);
    float logdet_sqrt = 0.f;
    for (int j = 0; j < D; ++j) logdet_sqrt += ld[j];
    logdet_sqrt *= 0.5f;
    float cc = 0.f;
    for (int d2 = 0; d2 < D; ++d2) cc += m_w[k * D + d2] * Gd[d2];
    // lc = logsoftmax - 8*ln(2pi) + 0.5*ln det L - 0.5 m^T L m, scaled log2e
    float lc = logp - 14.703016531274763f + logdet_sqrt - 0.5f * cc;
    lc_out[k] = LOG2E * lc;
  }
  __syncthreads();

  // theta in slot order, hi/lo bf16 split (truncation; lo holds residual)
  for (int q = tid; q < R; q += 256) {
    int d = TAB.pd[q], f = TAB.pf[q];
    float th;
    if (d == 17) th = 0.f;
    else if (f == 16) th = LOG2E * Gd[d];
    else th = ((d == f) ? -0.5f : -1.0f) * LOG2E * L[d][f];
    unsigned u = __float_as_uint(th);
    float hi = __uint_as_float(u & 0xFFFF0000u);
    float lo = th - hi;
    thetaH[k * R + q] = (unsigned short)(u >> 16);
    thetaL[k * R + q] = (unsigned short)(__float_as_uint(lo) >> 16);
  }
}

// pack 2 floats -> 2 bf16 (truncation) in one dword
__device__ __forceinline__ int pack_bf16_hi(unsigned u0, unsigned u1) {
  return (int)__builtin_amdgcn_perm(u1, u0, 0x07060302u);
}

// phi product for step S, reg J: all indices compile-time; kh select folds
// to (at most) 2 cndmasks, CSE'd across steps (xs, kh loop-invariant).
template<int S, int J>
__device__ __forceinline__ float prodSJ(const float (&xs)[18], int kh) {
  constexpr int A0 = TAB.a0[S*8+J], B0 = TAB.b0[S*8+J];
  constexpr int A1 = TAB.a1[S*8+J], B1 = TAB.b1[S*8+J];
  float u, v;
  if constexpr (A0 == A1) u = xs[A0]; else u = kh ? xs[A1] : xs[A0];
  if constexpr (B0 == B1) v = xs[B0]; else v = kh ? xs[B1] : xs[B0];
  return u * v;
}

template<int S>
__device__ __forceinline__ void build_phi(const float (&xs)[18], int kh,
                                          int4v& ph, int4v& pl) {
  float q[8];
  q[0] = prodSJ<S,0>(xs,kh); q[1] = prodSJ<S,1>(xs,kh);
  q[2] = prodSJ<S,2>(xs,kh); q[3] = prodSJ<S,3>(xs,kh);
  q[4] = prodSJ<S,4>(xs,kh); q[5] = prodSJ<S,5>(xs,kh);
  q[6] = prodSJ<S,6>(xs,kh); q[7] = prodSJ<S,7>(xs,kh);
  #pragma unroll
  for (int a = 0; a < 4; ++a) {
    unsigned u0 = __float_as_uint(q[2*a]), u1 = __float_as_uint(q[2*a+1]);
    ph[a] = pack_bf16_hi(u0, u1);
    float h0 = __uint_as_float(u0 & 0xFFFF0000u);
    float h1 = __uint_as_float(u1 & 0xFFFF0000u);
    pl[a] = pack_bf16_hi(__float_as_uint(q[2*a] - h0),
                         __float_as_uint(q[2*a+1] - h1));
  }
}

template<int S>
__device__ __forceinline__ void do_step(const float (&xs)[18], int kh,
    const char* lthp, int base2, int sigh, f32x16& acc) {
  // granule slot m = 2S+kh, phys = swizzle(m, sig); bit-decomposed:
  int va;
  if constexpr (S < 8) va = base2 + ((S ^ sigh) << 5);
  else                 va = base2 + 256 + (((S - 8) ^ (sigh & 1)) << 5);
  int4v thv = *(const int4v*)(lthp + va);
  int4v tlv = *(const int4v*)(lthp + va + LHALF);
  int4v ph, pl;
  build_phi<S>(xs, kh, ph, pl);
  acc = __builtin_amdgcn_mfma_f32_32x32x16_bf16(
      __builtin_bit_cast(bf16x8, thv), __builtin_bit_cast(bf16x8, ph), acc, 0, 0, 0);
  acc = __builtin_amdgcn_mfma_f32_32x32x16_bf16(
      __builtin_bit_cast(bf16x8, tlv), __builtin_bit_cast(bf16x8, ph), acc, 0, 0, 0);
  acc = __builtin_amdgcn_mfma_f32_32x32x16_bf16(
      __builtin_bit_cast(bf16x8, thv), __builtin_bit_cast(bf16x8, pl), acc, 0, 0, 0);
}

template<int... Ss>
__device__ __forceinline__ void all_steps(std::integer_sequence<int, Ss...>,
    const float (&xs)[18], int kh, const char* lthp, int base2, int sigh,
    f32x16& acc) {
  (do_step<Ss>(xs, kh, lthp, base2, sigh, acc), ...);
}

// ---------------- density kernel ----------------
// Triangle-packed features: R=160 -> 10 steps x 3 MFMA (hi*hi, lo*hi, hi*lo).
// Theta staged once per block into swizzled LDS (LROW=352B: 16p+4g bank walk
// + XOR sig spread -> conflict-free b128 reads). Persistent: 2 tiles/wave.
// NO min-waves launch bound (round-6 lesson: reg cap + overdemand = spills).
__global__ __launch_bounds__(256) void gm_mfma_kernel(
    const float* __restrict__ x,              // N*D
    const unsigned short* __restrict__ thetaH,
    const unsigned short* __restrict__ thetaL,
    const float* __restrict__ lc,             // K
    float* __restrict__ out)                  // N
{
  __shared__ __align__(16) char lth[2 * LHALF];
  const int tid = threadIdx.x;
  const int lane = tid & 63;
  const int p = lane & 31;          // point within tile / comp row for A
  const int kh = lane >> 5;         // k-half within 16-wide step

  // ---- stage theta -> LDS (swizzled): 2 halves x 32 rows x 20 granules
  for (int i = tid; i < 1280; i += 256) {
    int half = i >= 640;
    int g = half ? i - 640 : i;
    int row = g / 20;
    int m = g - row * 20;
    int sg = (row & 7) ^ (row >> 3);
    int phys = (m < 16) ? (m ^ sg) : (16 + ((m - 16) ^ (sg & 3)));
    const unsigned short* src = (half ? thetaL : thetaH) + row * R + m * 8;
    int4v v = *(const int4v*)src;
    *(int4v*)(lth + half * LHALF + row * LROW + phys * 16) = v;
  }

  // lc per accumulator register: comp = (i&3) + 8*(i>>2) + 4*kh
  float lcv[16];
  #pragma unroll
  for (int i = 0; i < 16; ++i)
    lcv[i] = lc[(i & 3) + 8 * (i >> 2) + 4 * kh];

  __syncthreads();

  const int sig = (p & 7) ^ (p >> 3);
  const int base2 = p * LROW + ((kh ^ (sig & 1)) << 4);
  const int sigh = sig >> 1;

  const int wid = blockIdx.x * 4 + (tid >> 6);

  #pragma unroll
  for (int tt = 0; tt < 2; ++tt) {
    const int t = wid * 2 + tt;
    float xs[18];
    const float4* xp = (const float4*)(x + ((size_t)t * 32 + p) * D);
    #pragma unroll
    for (int i = 0; i < 4; ++i) {
      float4 v = xp[i];
      xs[4*i+0] = v.x; xs[4*i+1] = v.y; xs[4*i+2] = v.z; xs[4*i+3] = v.w;
    }
    xs[16] = 1.0f;   // linear-term partner
    xs[17] = 0.0f;   // pad

    f32x16 acc;
    #pragma unroll
    for (int i = 0; i < 16; ++i) acc[i] = 0.f;

    all_steps(std::make_integer_sequence<int, NSTEPS>{}, xs, kh, lth,
              base2, sigh, acc);

    float e[16];
    #pragma unroll
    for (int i = 0; i < 16; ++i)
      e[i] = __builtin_amdgcn_exp2f(acc[i] + lcv[i]);
    float a0 = (e[0] + e[1]) + (e[2] + e[3]);
    float a1 = (e[4] + e[5]) + (e[6] + e[7]);
    float a2 = (e[8] + e[9]) + (e[10] + e[11]);
    float a3 = (e[12] + e[13]) + (e[14] + e[15]);
    float ss = (a0 + a1) + (a2 + a3);
    ss += __shfl_xor(ss, 32);
    if (lane < 32) out[(size_t)t * 32 + p] = ss;
  }
}

extern "C" void kernel_launch(void* const* d_in, const int* in_sizes, int n_in,
                              void* d_out, int out_size, void* d_ws, size_t ws_size,
                              hipStream_t stream) {
  const float* x        = (const float*)d_in[0];
  const float* m_w      = (const float*)d_in[1];
  const float* l_fac    = (const float*)d_in[2];
  const float* p_logits = (const float*)d_in[3];
  float* out = (float*)d_out;

  char* ws = (char*)d_ws;
  unsigned short* thetaH = (unsigned short*)(ws);                 // 10240 B
  unsigned short* thetaL = (unsigned short*)(ws + K * R * 2);     // 10240 B
  float* lc              = (float*)(ws + 2 * K * R * 2);          // 128 B

  gm_prep_kernel<<<K, 256, 0, stream>>>(m_w, l_fac, p_logits, thetaH, thetaL, lc);
  gm_mfma_kernel<<<NBLK, 256, 0, stream>>>(x, thetaH, thetaL, lc, out);
}

// Round 9
// 22.531 us; speedup vs baseline: 5.2094x; 1.0231x over previous
//
#include <hip/hip_runtime.h>
#include <math.h>
#include <utility>

#define NPTS 262144
#define K 32
#define D 16
#define R 160            // 136 triangle + 16 linear + 8 pad -> 10 MFMA K-steps
#define NSTEPS 10
#define NBLK 2048        // 4 waves/block, 1 tile/wave -> 8192 tiles
#define LROW 352         // 20 data granules (320 B) + 2 pad granules per row
#define LHALF 11264      // 32 rows * 352 B ; thetaL LDS region offset

typedef __attribute__((ext_vector_type(8))) short bf16x8;
typedef __attribute__((ext_vector_type(16))) float f32x16;
typedef __attribute__((ext_vector_type(4))) int int4v;

// ---- compile-time slot table -------------------------------------------
// 80 cells; cell c=(S,j) holds slot S*16+j (kh=0: u0,v0) and S*16+8+j
// (kh=1: u1,v1).  Pairing chosen so u0==u1 for all but 4 cells -> the
// kh-select on the first factor vanishes (cndmask count ~140 -> ~76).
//   - quad entries (d,f) d<=f paired within row d (u=d shared)
//   - odd-row leftovers (d,15) paired cross-row (v=15 shared)
//   - linear terms stored as (16,d): u==1 for both halves
//   - pads (17,17): theta=0, product folds to 0
struct PTab {
  short pd[160], pf[160];               // per slot (prep kernel)
  short u0[80], v0[80], u1[80], v1[80]; // per cell (density kernel)
  constexpr PTab() : pd{}, pf{}, u0{}, v0{}, u1{}, v1{} {
    int nc = 0;
    for (int d = 0; d < 16; ++d) {
      int f = d;
      while (f + 1 <= 15) {
        u0[nc] = (short)d; v0[nc] = (short)f;
        u1[nc] = (short)d; v1[nc] = (short)(f + 1);
        ++nc; f += 2;
      }
    }
    for (int i = 0; i < 4; ++i) {       // leftovers (1,15)(3,15)...(15,15)
      u0[nc] = (short)(4*i+1); v0[nc] = 15;
      u1[nc] = (short)(4*i+3); v1[nc] = 15; ++nc;
    }
    for (int i = 0; i < 8; ++i) {       // linear: u==1 (index 16)
      u0[nc] = 16; v0[nc] = (short)(2*i);
      u1[nc] = 16; v1[nc] = (short)(2*i+1); ++nc;
    }
    for (int i = 0; i < 4; ++i) {       // pads
      u0[nc] = 17; v0[nc] = 17; u1[nc] = 17; v1[nc] = 17; ++nc;
    }
    for (int c = 0; c < 80; ++c) {
      int S = c / 8, j = c % 8;
      pd[S*16 + j]     = u0[c]; pf[S*16 + j]     = v0[c];
      pd[S*16 + 8 + j] = u1[c]; pf[S*16 + 8 + j] = v1[c];
    }
  }
};
static constexpr PTab TAB{};

// ---------------- prep kernel: one block per component k ----------------
__global__ __launch_bounds__(256) void gm_prep_kernel(
    const float* __restrict__ m_w,      // K*D
    const float* __restrict__ l_fac,    // K*D*D
    const float* __restrict__ p_logits, // K
    unsigned short* __restrict__ thetaH, // K*R bf16 bits
    unsigned short* __restrict__ thetaL, // K*R bf16 bits
    float* __restrict__ lc_out)          // K
{
  const int k = blockIdx.x;
  const int tid = threadIdx.x;
  const int r = tid >> 4, c = tid & 15;
  __shared__ float A[D][D];
  __shared__ float L[D][D];
  __shared__ float S[2][D][D];   // LDL double buffer
  __shared__ float Gd[D];
  __shared__ float ld[D];        // log pivots
  __shared__ float sm[K];
  const float LOG2E = 1.4426950408889634f;

  A[r][c] = l_fac[k * D * D + r * D + c];
  if (tid < K) sm[tid] = p_logits[tid];
  __syncthreads();

  // L = A A^T / D
  {
    float s = 0.f;
    #pragma unroll
    for (int e = 0; e < D; ++e) s += A[r][e] * A[c][e];
    s *= (1.0f / D);
    L[r][c] = s;
    S[0][r][c] = s;
  }
  __syncthreads();

  // G = L m
  if (tid < D) {
    float s = 0.f;
    #pragma unroll
    for (int f = 0; f < D; ++f) s += L[tid][f] * m_w[k * D + f];
    Gd[tid] = s;
  }

  // LDL pivots via Schur complements, 1 sync per step
  int cb = 0;
  for (int j = 0; j < 15; ++j) {
    float pj = S[cb][j][j];
    float a = S[cb][r][j], b = S[cb][c][j], v = S[cb][r][c];
    if (tid == 0) ld[j] = logf(pj);
    if (r > j && c > j) S[cb ^ 1][r][c] = v - a * b / pj;
    cb ^= 1;
    __syncthreads();
  }
  if (tid == 0) {
    ld[15] = logf(S[cb][15][15]);
    float mx = -1e30f;
    for (int i = 0; i < K; ++i) mx = fmaxf(mx, sm[i]);
    float z = 0.f;
    for (int i = 0; i < K; ++i) z += expf(sm[i] - mx);
    float logp = sm[k] - mx - logf(z);
    float logdet_sqrt = 0.f;
    for (int j = 0; j < D; ++j) logdet_sqrt += ld[j];
    logdet_sqrt *= 0.5f;
    float cc = 0.f;
    for (int d2 = 0; d2 < D; ++d2) cc += m_w[k * D + d2] * Gd[d2];
    float lc = logp - 14.703016531274763f + logdet_sqrt - 0.5f * cc;
    lc_out[k] = LOG2E * lc;
  }
  __syncthreads();

  // theta in slot order, hi/lo bf16 split (truncation; lo holds residual)
  for (int q = tid; q < R; q += 256) {
    int d = TAB.pd[q], f = TAB.pf[q];
    float th;
    if (d == 17) th = 0.f;
    else if (d == 16) th = LOG2E * Gd[f];
    else th = ((d == f) ? -0.5f : -1.0f) * LOG2E * L[d][f];
    unsigned u = __float_as_uint(th);
    float hi = __uint_as_float(u & 0xFFFF0000u);
    float lo = th - hi;
    thetaH[k * R + q] = (unsigned short)(u >> 16);
    thetaL[k * R + q] = (unsigned short)(__float_as_uint(lo) >> 16);
  }
}

// pack 2 floats -> 2 bf16 (truncation) in one dword
__device__ __forceinline__ int pack_bf16_hi(unsigned u0, unsigned u1) {
  return (int)__builtin_amdgcn_perm(u1, u0, 0x07060302u);
}

// phi product for cell (S,J): indices compile-time; at most one cndmask.
template<int S, int J>
__device__ __forceinline__ float prodSJ(const float (&xs)[16], int kh) {
  constexpr int U0 = TAB.u0[S*8+J], V0 = TAB.v0[S*8+J];
  constexpr int U1 = TAB.u1[S*8+J], V1 = TAB.v1[S*8+J];
  if constexpr (U0 == 17) {
    return 0.0f;                              // pad
  } else if constexpr (U0 == 16) {            // linear: u == 1
    if constexpr (V0 == V1) return xs[V0];
    else return kh ? xs[V1] : xs[V0];
  } else {
    float u, v;
    if constexpr (U0 == U1) u = xs[U0]; else u = kh ? xs[U1] : xs[U0];
    if constexpr (V0 == V1) v = xs[V0]; else v = kh ? xs[V1] : xs[V0];
    return u * v;
  }
}

template<int S>
__device__ __forceinline__ void build_phi(const float (&xs)[16], int kh,
                                          int4v& ph, int4v& pl) {
  float q[8];
  q[0] = prodSJ<S,0>(xs,kh); q[1] = prodSJ<S,1>(xs,kh);
  q[2] = prodSJ<S,2>(xs,kh); q[3] = prodSJ<S,3>(xs,kh);
  q[4] = prodSJ<S,4>(xs,kh); q[5] = prodSJ<S,5>(xs,kh);
  q[6] = prodSJ<S,6>(xs,kh); q[7] = prodSJ<S,7>(xs,kh);
  #pragma unroll
  for (int a = 0; a < 4; ++a) {
    unsigned u0 = __float_as_uint(q[2*a]), u1 = __float_as_uint(q[2*a+1]);
    ph[a] = pack_bf16_hi(u0, u1);
    float h0 = __uint_as_float(u0 & 0xFFFF0000u);
    float h1 = __uint_as_float(u1 & 0xFFFF0000u);
    pl[a] = pack_bf16_hi(__float_as_uint(q[2*a] - h0),
                         __float_as_uint(q[2*a+1] - h1));
  }
}

template<int S>
__device__ __forceinline__ void do_step(const float (&xs)[16], int kh,
    const char* lthp, int base2, int sigh, f32x16& acc) {
  int va;
  if constexpr (S < 8) va = base2 + ((S ^ sigh) << 5);
  else                 va = base2 + 256 + (((S - 8) ^ (sigh & 1)) << 5);
  int4v thv = *(const int4v*)(lthp + va);
  int4v tlv = *(const int4v*)(lthp + va + LHALF);
  int4v ph, pl;
  build_phi<S>(xs, kh, ph, pl);
  acc = __builtin_amdgcn_mfma_f32_32x32x16_bf16(
      __builtin_bit_cast(bf16x8, thv), __builtin_bit_cast(bf16x8, ph), acc, 0, 0, 0);
  acc = __builtin_amdgcn_mfma_f32_32x32x16_bf16(
      __builtin_bit_cast(bf16x8, tlv), __builtin_bit_cast(bf16x8, ph), acc, 0, 0, 0);
  acc = __builtin_amdgcn_mfma_f32_32x32x16_bf16(
      __builtin_bit_cast(bf16x8, thv), __builtin_bit_cast(bf16x8, pl), acc, 0, 0, 0);
}

template<int... Ss>
__device__ __forceinline__ void all_steps(std::integer_sequence<int, Ss...>,
    const float (&xs)[16], int kh, const char* lthp, int base2, int sigh,
    f32x16& acc) {
  (do_step<Ss>(xs, kh, lthp, base2, sigh, acc), ...);
}

// ---------------- density kernel: 1 tile per wave ----------------
// x loads issued BEFORE staging so HBM latency hides under staging+barrier.
// Single-tile body: minimal live ranges (round-6/8 lesson: no unroll
// multiplier on the fully-unrolled 10-step chain). No min-waves bound.
__global__ __launch_bounds__(256) void gm_mfma_kernel(
    const float* __restrict__ x,              // N*D
    const unsigned short* __restrict__ thetaH,
    const unsigned short* __restrict__ thetaL,
    const float* __restrict__ lc,             // K
    float* __restrict__ out)                  // N
{
  __shared__ __align__(16) char lth[2 * LHALF];
  const int tid = threadIdx.x;
  const int lane = tid & 63;
  const int p = lane & 31;          // point within tile / comp row for A
  const int kh = lane >> 5;         // k-half within 16-wide step
  const int t = blockIdx.x * 4 + (tid >> 6);   // tile = wave

  // issue x loads first (4 dwordx4 in flight across staging)
  const float4* xp = (const float4*)(x + ((size_t)t * 32 + p) * D);
  float4 xv0 = xp[0], xv1 = xp[1], xv2 = xp[2], xv3 = xp[3];

  // ---- stage theta -> LDS (swizzled): 2 halves x 32 rows x 20 granules
  for (int i = tid; i < 1280; i += 256) {
    int half = i >= 640;
    int g = half ? i - 640 : i;
    int row = g / 20;
    int m = g - row * 20;
    int sg = (row & 7) ^ (row >> 3);
    int phys = (m < 16) ? (m ^ sg) : (16 + ((m - 16) ^ (sg & 3)));
    const unsigned short* src = (half ? thetaL : thetaH) + row * R + m * 8;
    int4v v = *(const int4v*)src;
    *(int4v*)(lth + half * LHALF + row * LROW + phys * 16) = v;
  }

  // lc per accumulator register: comp = (i&3) + 8*(i>>2) + 4*kh
  float lcv[16];
  #pragma unroll
  for (int i = 0; i < 16; ++i)
    lcv[i] = lc[(i & 3) + 8 * (i >> 2) + 4 * kh];

  __syncthreads();

  const int sig = (p & 7) ^ (p >> 3);
  const int base2 = p * LROW + ((kh ^ (sig & 1)) << 4);
  const int sigh = sig >> 1;

  float xs[16];
  xs[0]=xv0.x; xs[1]=xv0.y; xs[2]=xv0.z; xs[3]=xv0.w;
  xs[4]=xv1.x; xs[5]=xv1.y; xs[6]=xv1.z; xs[7]=xv1.w;
  xs[8]=xv2.x; xs[9]=xv2.y; xs[10]=xv2.z; xs[11]=xv2.w;
  xs[12]=xv3.x; xs[13]=xv3.y; xs[14]=xv3.z; xs[15]=xv3.w;

  f32x16 acc;
  #pragma unroll
  for (int i = 0; i < 16; ++i) acc[i] = 0.f;

  all_steps(std::make_integer_sequence<int, NSTEPS>{}, xs, kh, lth,
            base2, sigh, acc);

  float e[16];
  #pragma unroll
  for (int i = 0; i < 16; ++i)
    e[i] = __builtin_amdgcn_exp2f(acc[i] + lcv[i]);
  float a0 = (e[0] + e[1]) + (e[2] + e[3]);
  float a1 = (e[4] + e[5]) + (e[6] + e[7]);
  float a2 = (e[8] + e[9]) + (e[10] + e[11]);
  float a3 = (e[12] + e[13]) + (e[14] + e[15]);
  float ss = (a0 + a1) + (a2 + a3);
  ss += __shfl_xor(ss, 32);
  if (lane < 32) out[(size_t)t * 32 + p] = ss;
}

extern "C" void kernel_launch(void* const* d_in, const int* in_sizes, int n_in,
                              void* d_out, int out_size, void* d_ws, size_t ws_size,
                              hipStream_t stream) {
  const float* x        = (const float*)d_in[0];
  const float* m_w      = (const float*)d_in[1];
  const float* l_fac    = (const float*)d_in[2];
  const float* p_logits = (const float*)d_in[3];
  float* out = (float*)d_out;

  char* ws = (char*)d_ws;
  unsigned short* thetaH = (unsigned short*)(ws);                 // 10240 B
  unsigned short* thetaL = (unsigned short*)(ws + K * R * 2);     // 10240 B
  float* lc              = (float*)(ws + 2 * K * R * 2);          // 128 B

  gm_prep_kernel<<<K, 256, 0, stream>>>(m_w, l_fac, p_logits, thetaH, thetaL, lc);
  gm_mfma_kernel<<<NBLK, 256, 0, stream>>>(x, thetaH, thetaL, lc, out);
}